// Round 2
// baseline (3414.175 us; speedup 1.0000x reference)
//
#include <hip/hip_runtime.h>
#include <math.h>

#define L_    4
#define B_    1024
#define IN_   512
#define OUT_  512
#define DM_   1024
#define DS_   16
#define DC_   4
#define DI_   2048
#define DTR_  64
#define NST_  20      // DC + DS
#define XZW_  4096    // 2*DI
#define XDBW_ 96      // DTR + 2*DS

// ---------------------------------------------------------------------------
// Generic fp32 GEMM: C[m][n] = act(sum_k A[m*lda+k] * W[n*ldw+k] (+ bias[n]))
// A: (M, K) row-major stride lda, W: (N, K) row-major stride ldw.
// ACT: 0 = none, 1 = +bias
// ---------------------------------------------------------------------------
template<int BM, int BN, int BK, int TM, int TN, int ACT>
__global__ __launch_bounds__(256)
void gemm_nt(const float* __restrict__ A, int lda,
             const float* __restrict__ W, int ldw,
             const float* __restrict__ bias,
             float* __restrict__ C, int ldc, int K)
{
    constexpr int TX = BN / TN;
    constexpr int TY = BM / TM;
    static_assert(TX * TY == 256, "bad tile config");
    __shared__ float As[BK][BM + 4];
    __shared__ float Ws[BK][BN + 4];

    const int tid = threadIdx.x;
    const int tx  = tid % TX, ty = tid / TX;
    const int bm  = blockIdx.y * BM, bn = blockIdx.x * BN;

    A += (size_t)bm * lda;
    W += (size_t)bn * ldw;

    float acc[TM][TN] = {};

    for (int k0 = 0; k0 < K; k0 += BK) {
        // ---- stage A tile (BM x BK) into As[k][m] ----
        static_assert((BM * BK) % 1024 == 0 && (BN * BK) % 1024 == 0, "tile");
        #pragma unroll
        for (int i = 0; i < BM * BK / 1024; ++i) {
            int idx = tid + i * 256;
            int kq  = idx % (BK / 4);
            int row = idx / (BK / 4);
            float4 v = *(const float4*)(A + (size_t)row * lda + k0 + kq * 4);
            As[kq*4+0][row] = v.x; As[kq*4+1][row] = v.y;
            As[kq*4+2][row] = v.z; As[kq*4+3][row] = v.w;
        }
        // ---- stage W tile (BN x BK) into Ws[k][n] ----
        #pragma unroll
        for (int i = 0; i < BN * BK / 1024; ++i) {
            int idx = tid + i * 256;
            int kq  = idx % (BK / 4);
            int col = idx / (BK / 4);
            float4 v = *(const float4*)(W + (size_t)col * ldw + k0 + kq * 4);
            Ws[kq*4+0][col] = v.x; Ws[kq*4+1][col] = v.y;
            Ws[kq*4+2][col] = v.z; Ws[kq*4+3][col] = v.w;
        }
        __syncthreads();

        #pragma unroll
        for (int kk = 0; kk < BK; ++kk) {
            float ra[TM], rb[TN];
            #pragma unroll
            for (int i = 0; i < TM; i += 4)
                *(float4*)&ra[i] = *(const float4*)&As[kk][ty * TM + i];
            #pragma unroll
            for (int j = 0; j < TN; j += 4)
                *(float4*)&rb[j] = *(const float4*)&Ws[kk][tx * TN + j];
            #pragma unroll
            for (int i = 0; i < TM; ++i)
                #pragma unroll
                for (int j = 0; j < TN; ++j)
                    acc[i][j] = fmaf(ra[i], rb[j], acc[i][j]);
        }
        __syncthreads();
    }

    // ---- epilogue ----
    #pragma unroll
    for (int i = 0; i < TM; ++i) {
        const size_t crow = (size_t)(bm + ty * TM + i) * ldc;
        #pragma unroll
        for (int j = 0; j < TN; ++j) {
            const int n = bn + tx * TN + j;
            float v = acc[i][j];
            if constexpr (ACT >= 1) v += bias[n];
            C[crow + n] = v;
        }
    }
}

// ---------------------------------------------------------------------------
// Residual + LayerNorm.  MODE 0: resid = h; MODE 1: resid += h;
// MODE 2: t = h + resid (final, resid not written). out = LN(t)*w + b.
// One block per row (1024 cols, 256 threads, float4 each).
// ---------------------------------------------------------------------------
template<int MODE>
__global__ __launch_bounds__(256)
void resid_ln(const float* __restrict__ h, float* __restrict__ resid,
              const float* __restrict__ w, const float* __restrict__ b,
              float* __restrict__ out)
{
    const int row = blockIdx.x;
    const int t   = threadIdx.x;
    const size_t base = (size_t)row * DM_;

    float4 v = ((const float4*)(h + base))[t];
    if (MODE >= 1) {
        float4 r = ((const float4*)(resid + base))[t];
        v.x += r.x; v.y += r.y; v.z += r.z; v.w += r.w;
    }
    if (MODE <= 1) ((float4*)(resid + base))[t] = v;

    float s = v.x + v.y + v.z + v.w;
    float q = v.x*v.x + v.y*v.y + v.z*v.z + v.w*v.w;
    #pragma unroll
    for (int off = 32; off >= 1; off >>= 1) {
        s += __shfl_down(s, off, 64);
        q += __shfl_down(q, off, 64);
    }
    __shared__ float sm[8];
    const int wid = t >> 6, lane = t & 63;
    if (lane == 0) { sm[wid] = s; sm[wid + 4] = q; }
    __syncthreads();
    s = sm[0] + sm[1] + sm[2] + sm[3];
    q = sm[4] + sm[5] + sm[6] + sm[7];

    const float mu   = s * (1.f / DM_);
    const float var  = q * (1.f / DM_) - mu * mu;
    const float rstd = rsqrtf(var + 1e-5f);

    float4 wv = ((const float4*)w)[t];
    float4 bv = ((const float4*)b)[t];
    float4 o;
    o.x = (v.x - mu) * rstd * wv.x + bv.x;
    o.y = (v.y - mu) * rstd * wv.y + bv.y;
    o.z = (v.z - mu) * rstd * wv.z + bv.z;
    o.w = (v.w - mu) * rstd * wv.w + bv.w;
    ((float4*)(out + base))[t] = o;
}

// ---------------------------------------------------------------------------
// Fused per-layer scan: conv-shift + SiLU -> x_proj -> dt_proj/softplus ->
// SSM state update -> gate.  One block per batch row b, 512 threads, each
// thread owns channels d = t + i*512 (i<4).  State record (20 floats) is
// read ONCE (conv head consumed, SSM tail parked in registers) and written
// ONCE.  x_proj/dt_proj weights are small (786KB/512KB) -> L2-resident
// across the 1024 blocks.
// ---------------------------------------------------------------------------
#define SBLK 512
__global__ __launch_bounds__(SBLK)
void fused_scan(const float* __restrict__ st_in,    // (B*DI)*20 layer base
                const float* __restrict__ xz,       // B x 4096
                const float* __restrict__ convW,    // DI x 4
                const float* __restrict__ convB,    // DI
                const float* __restrict__ x_projW,  // 96 x 2048
                const float* __restrict__ dt_projW, // 2048 x 64
                const float* __restrict__ dt_projB, // 2048
                const float* __restrict__ A_log,    // DI x 16 (layer slice)
                const float* __restrict__ Dv,       // DI
                float* __restrict__ st_out,         // layer base in d_out
                float* __restrict__ ybuf)           // B x DI
{
    const int b = blockIdx.x;
    const int t = threadIdx.x;
    __shared__ float xs_s[DI_];
    __shared__ float xdb_s[XDBW_];

    float ss[4][16];     // SSM state, statically indexed -> registers
    float xsv[4], dtv[4];

    const float* stb_in  = st_in  + (size_t)b * DI_ * NST_;
    float*       stb_out = st_out + (size_t)b * DI_ * NST_;
    const float* xzrow   = xz + (size_t)b * XZW_;

    // ---- stage 1: read full state record, conv + SiLU ----
    #pragma unroll
    for (int i = 0; i < 4; ++i) {
        const int d = t + i * SBLK;
        const float* rec = stb_in + (size_t)d * NST_;
        float4 c = *(const float4*)rec;
        #pragma unroll
        for (int n = 0; n < 16; n += 4) {
            float4 s4 = *(const float4*)(rec + DC_ + n);
            ss[i][n+0] = s4.x; ss[i][n+1] = s4.y;
            ss[i][n+2] = s4.z; ss[i][n+3] = s4.w;
        }
        const float xc = xzrow[d];
        float4 w = *(const float4*)(convW + d * 4);
        float s = c.y * w.x + c.z * w.y + c.w * w.z + xc * w.w + convB[d];
        float v = s / (1.f + expf(-s));
        xsv[i]  = v;
        xs_s[d] = v;
        *(float4*)(stb_out + (size_t)d * NST_) = make_float4(c.y, c.z, c.w, xc);
    }
    __syncthreads();

    // ---- stage 2: xdb[96] = xs @ x_projW.T (wave-parallel dots) ----
    {
        const int wv = t >> 6, ln = t & 63;
        #pragma unroll
        for (int jj = 0; jj < 12; ++jj) {
            const int j = wv * 12 + jj;
            const float* wr = x_projW + (size_t)j * DI_;
            float p = 0.f;
            #pragma unroll
            for (int k = 0; k < DI_ / 256; ++k) {       // 8 iters of float4
                const int d = 4 * ln + 256 * k;
                float4 w4 = *(const float4*)(wr + d);
                float4 x4 = *(const float4*)(xs_s + d);
                p += x4.x*w4.x + x4.y*w4.y + x4.z*w4.z + x4.w*w4.w;
            }
            #pragma unroll
            for (int off = 32; off >= 1; off >>= 1) p += __shfl_down(p, off, 64);
            if (ln == 0) xdb_s[j] = p;
        }
    }
    __syncthreads();

    // ---- stage 3: dt[d] = softplus(xdb[0:64] . dt_projW[d] + b[d]) ----
    #pragma unroll
    for (int i = 0; i < 4; ++i) {
        const int d = t + i * SBLK;
        const float* wr = dt_projW + (size_t)d * DTR_;
        float acc = dt_projB[d];
        #pragma unroll
        for (int r = 0; r < DTR_; r += 4) {
            float4 w4 = *(const float4*)(wr + r);
            acc += xdb_s[r+0]*w4.x + xdb_s[r+1]*w4.y
                 + xdb_s[r+2]*w4.z + xdb_s[r+3]*w4.w;
        }
        dtv[i] = fmaxf(acc, 0.f) + log1pf(expf(-fabsf(acc)));  // softplus
    }
    // xdb_s is read-only from here; no barrier needed before stage 4.

    // ---- stage 4: SSM update + y + gate ----
    #pragma unroll
    for (int i = 0; i < 4; ++i) {
        const int d  = t + i * SBLK;
        const float dt   = dtv[i];
        const float xv   = xsv[i];
        const float dtxs = dt * xv;
        const float* al  = A_log + (size_t)d * DS_;
        float* so = stb_out + (size_t)d * NST_ + DC_;
        float y = 0.f;
        #pragma unroll
        for (int n = 0; n < DS_; n += 4) {
            float4 a4 = *(const float4*)(al + n);
            float4 o4;
            o4.x = ss[i][n+0] * expf(-dt * expf(a4.x)) + dtxs * xdb_s[DTR_ + n + 0];
            o4.y = ss[i][n+1] * expf(-dt * expf(a4.y)) + dtxs * xdb_s[DTR_ + n + 1];
            o4.z = ss[i][n+2] * expf(-dt * expf(a4.z)) + dtxs * xdb_s[DTR_ + n + 2];
            o4.w = ss[i][n+3] * expf(-dt * expf(a4.w)) + dtxs * xdb_s[DTR_ + n + 3];
            y += o4.x * xdb_s[DTR_ + DS_ + n + 0]
               + o4.y * xdb_s[DTR_ + DS_ + n + 1]
               + o4.z * xdb_s[DTR_ + DS_ + n + 2]
               + o4.w * xdb_s[DTR_ + DS_ + n + 3];
            *(float4*)(so + n) = o4;
        }
        y += Dv[d] * xv;
        const float z = xzrow[DI_ + d];
        y *= z / (1.f + expf(-z));                 // silu gate
        ybuf[(size_t)b * DI_ + d] = y;
    }
}

// ---------------------------------------------------------------------------
extern "C" void kernel_launch(void* const* d_in, const int* in_sizes, int n_in,
                              void* d_out, int out_size, void* d_ws, size_t ws_size,
                              hipStream_t stream)
{
    (void)in_sizes; (void)n_in; (void)out_size; (void)ws_size;

    const float* x        = (const float*)d_in[0];
    const float* rnn      = (const float*)d_in[1];
    const float* W_in     = (const float*)d_in[2];
    const float* b_in     = (const float*)d_in[3];
    const float* W_out    = (const float*)d_in[4];
    const float* b_out    = (const float*)d_in[5];
    const float* in_projW = (const float*)d_in[6];
    const float* convW    = (const float*)d_in[7];
    const float* convB    = (const float*)d_in[8];
    const float* x_projW  = (const float*)d_in[9];
    const float* dt_projW = (const float*)d_in[10];
    const float* dt_projB = (const float*)d_in[11];
    const float* A_log    = (const float*)d_in[12];
    const float* Dvec     = (const float*)d_in[13];
    const float* out_projW= (const float*)d_in[14];
    const float* norm_w   = (const float*)d_in[15];
    const float* norm_b   = (const float*)d_in[16];
    const float* normf_w  = (const float*)d_in[17];
    const float* normf_b  = (const float*)d_in[18];

    float* out        = (float*)d_out;                 // (B, OUT) = 524288
    float* states_out = out + (size_t)B_ * OUT_;       // (L,B,DI,20)

    float* ws    = (float*)d_ws;
    float* h     = ws;                         // B*DM
    float* resid = h     + (size_t)B_ * DM_;   // B*DM
    float* hn    = resid + (size_t)B_ * DM_;   // B*DM
    float* xz    = hn    + (size_t)B_ * DM_;   // B*4096
    float* ybuf  = xz    + (size_t)B_ * XZW_;  // B*DI

    // h = x @ W_in.T + b_in   (M=1024, N=1024, K=512)
    gemm_nt<64,64,16,4,4,1><<<dim3(DM_/64, B_/64), 256, 0, stream>>>(
        x, IN_, W_in, IN_, b_in, h, DM_, IN_);

    const int nBD = B_ * DI_;
    for (int l = 0; l < L_; ++l) {
        const float* st_in  = rnn        + (size_t)l * nBD * NST_;
        float*       st_out = states_out + (size_t)l * nBD * NST_;

        // residual update + layernorm
        if (l == 0)
            resid_ln<0><<<B_, 256, 0, stream>>>(h, resid, norm_w + l*DM_, norm_b + l*DM_, hn);
        else
            resid_ln<1><<<B_, 256, 0, stream>>>(h, resid, norm_w + l*DM_, norm_b + l*DM_, hn);

        // xz = hn @ in_proj_W[l].T   (M=1024, N=4096, K=1024)
        gemm_nt<128,128,8,8,8,0><<<dim3(XZW_/128, B_/128), 256, 0, stream>>>(
            hn, DM_, in_projW + (size_t)l * XZW_ * DM_, DM_, nullptr, xz, XZW_, DM_);

        // fused conv + x_proj + dt_proj + ssm + gate
        fused_scan<<<B_, SBLK, 0, stream>>>(
            st_in, xz,
            convW + (size_t)l * DI_ * DC_, convB + (size_t)l * DI_,
            x_projW + (size_t)l * XDBW_ * DI_,
            dt_projW + (size_t)l * DI_ * DTR_, dt_projB + (size_t)l * DI_,
            A_log + (size_t)l * DI_ * DS_, Dvec + (size_t)l * DI_,
            st_out, ybuf);

        // h = y @ out_proj_W[l].T   (M=1024, N=1024, K=2048)
        gemm_nt<64,64,16,4,4,0><<<dim3(DM_/64, B_/64), 256, 0, stream>>>(
            ybuf, DI_, out_projW + (size_t)l * DM_ * DI_, DI_, nullptr, h, DM_, DI_);
    }

    // final layernorm of (h + residual)
    resid_ln<2><<<B_, 256, 0, stream>>>(h, resid, normf_w, normf_b, hn);

    // out = hn @ W_out.T + b_out   (M=1024, N=512, K=1024)
    gemm_nt<64,64,16,4,4,1><<<dim3(OUT_/64, B_/64), 256, 0, stream>>>(
        hn, DM_, W_out, DM_, b_out, out, OUT_, DM_);
}